// Round 1
// baseline (212.820 us; speedup 1.0000x reference)
//
#include <hip/hip_runtime.h>

typedef __attribute__((ext_vector_type(8))) __bf16 bfv8;
typedef __attribute__((ext_vector_type(4))) float f4v;
typedef __attribute__((ext_vector_type(4))) unsigned short us4v;
typedef __attribute__((ext_vector_type(8))) unsigned short us8v;

static __device__ __forceinline__ unsigned short f2bf(float f){
  union { float f; unsigned u; } v; v.f = f;
  unsigned r = v.u + 0x7fffu + ((v.u >> 16) & 1u);
  return (unsigned short)(r >> 16);
}

static __device__ __forceinline__ f4v mfma16(bfv8 a, bfv8 b, f4v c){
  return __builtin_amdgcn_mfma_f32_16x16x32_bf16(a, b, c, 0, 0, 0);
}

// ---------------- K0: fp32 -> bf16 convert (weights) ----------------
__global__ __launch_bounds__(256) void k_cvt(const float* __restrict__ src,
                                             unsigned short* __restrict__ dst){
  int i = blockIdx.x * 256 + threadIdx.x;
  float4 v = ((const float4*)src)[i];
  us4v o; o[0]=f2bf(v.x); o[1]=f2bf(v.y); o[2]=f2bf(v.z); o[3]=f2bf(v.w);
  *(us4v*)(dst + (size_t)i*4) = o;
}

// ---------------- K1: GroupNorm partial stats ----------------
// grid 256 = 16 (b,g) x 16 chunks; each group is a contiguous 131072-float span
__global__ __launch_bounds__(256) void k_gnstat(const float* __restrict__ x,
                                                float2* __restrict__ part){
  int bg = blockIdx.x >> 4, ch = blockIdx.x & 15;
  const float4* base = (const float4*)(x + (size_t)bg*131072 + (size_t)ch*8192);
  float s=0.f, ss=0.f;
  #pragma unroll
  for (int it=0; it<8; ++it){
    float4 v = base[threadIdx.x + it*256];
    s  += v.x+v.y+v.z+v.w;
    ss += v.x*v.x+v.y*v.y+v.z*v.z+v.w*v.w;
  }
  #pragma unroll
  for (int off=1; off<64; off<<=1){ s += __shfl_xor(s,off); ss += __shfl_xor(ss,off); }
  __shared__ float red[8];
  int wid = threadIdx.x >> 6, l = threadIdx.x & 63;
  if (l==0){ red[wid]=s; red[wid+4]=ss; }
  __syncthreads();
  if (threadIdx.x==0)
    part[blockIdx.x] = make_float2(red[0]+red[1]+red[2]+red[3],
                                   red[4]+red[5]+red[6]+red[7]);
}

// ---------------- K2: GroupNorm finalize + transpose to hT[b][n][c] bf16 ----------------
// grid 512 = b(2) x ctile(8) x ntile(32); ctile == group (64 ch)
__global__ __launch_bounds__(256) void k_gnnorm(const float* __restrict__ x,
                                                const float2* __restrict__ part,
                                                const float* __restrict__ gnw,
                                                const float* __restrict__ gnb,
                                                unsigned short* __restrict__ hT){
  int nt = blockIdx.x & 31, ct = (blockIdx.x>>5)&7, b = blockIdx.x>>8;
  __shared__ float2 sms;
  __shared__ unsigned short tile[64][68];
  int tid = threadIdx.x;
  if (tid == 0){
    int bg = b*8 + ct;
    float s=0.f, ss=0.f;
    for (int i=0;i<16;++i){ float2 p = part[bg*16+i]; s+=p.x; ss+=p.y; }
    float mean = s * (1.f/131072.f);
    float var  = ss * (1.f/131072.f) - mean*mean;
    sms = make_float2(mean, rsqrtf(var + 1e-5f));
  }
  __syncthreads();
  float mean = sms.x, rstd = sms.y;
  int c0 = ct*64, n0 = nt*64;
  #pragma unroll
  for (int pass=0; pass<4; ++pass){
    int i = (tid>>4) + pass*16;
    int fc = tid & 15;
    int c = c0 + i;
    float w  = gnw[c]*rstd;
    float bb = gnb[c] - mean*w;
    float4 v = *(const float4*)(x + ((size_t)(b*512+c))*2048 + n0 + fc*4);
    tile[i][fc*4+0] = f2bf(v.x*w+bb);
    tile[i][fc*4+1] = f2bf(v.y*w+bb);
    tile[i][fc*4+2] = f2bf(v.z*w+bb);
    tile[i][fc*4+3] = f2bf(v.w*w+bb);
  }
  __syncthreads();
  #pragma unroll
  for (int pass=0; pass<2; ++pass){
    int r  = (tid>>3) + pass*32;
    int c8 = tid & 7;
    us8v o;
    #pragma unroll
    for (int u=0;u<8;++u) o[u] = tile[c8*8+u][r];
    *(us8v*)(hT + ((size_t)(b*2048 + n0 + r))*512 + c0 + c8*8) = o;
  }
}

// ---------------- K3: qkv GEMM  Yt[n,o] = hT[n,:] . w[o,:] + b ----------------
// grid 768 = b(2) x ntile(32) x otile(12); block 4 waves; wave: 16 n-rows x 128 o-cols
__global__ __launch_bounds__(256) void k_qkv(const unsigned short* __restrict__ hT,
                                             const unsigned short* __restrict__ wb,
                                             const float* __restrict__ qb,
                                             unsigned short* __restrict__ Qh,
                                             unsigned short* __restrict__ Kh,
                                             unsigned short* __restrict__ Vt){
  int bid = blockIdx.x;
  int ot = bid % 12; int t2 = bid / 12; int nt = t2 & 31; int b = t2 >> 5;
  int tid = threadIdx.x, wid = tid>>6, l = tid&63, lr = l&15, lg = l>>4;
  int n0 = nt*64 + wid*16, o0 = ot*128;
  f4v acc[8];
  #pragma unroll
  for (int s=0;s<8;++s) acc[s] = (f4v){0.f,0.f,0.f,0.f};
  const unsigned short* arow = hT + ((size_t)(b*2048 + n0 + lr))*512 + lg*8;
  const unsigned short* brow = wb + (size_t)(o0 + lr)*512 + lg*8;
  for (int k=0;k<512;k+=32){
    bfv8 a = *(const bfv8*)(arow + k);
    #pragma unroll
    for (int s=0;s<8;++s){
      bfv8 bb = *(const bfv8*)(brow + s*8192 + k);
      acc[s] = mfma16(a, bb, acc[s]);
    }
  }
  #pragma unroll
  for (int s=0;s<8;++s){
    int o = o0 + s*16 + lr;
    float bias = qb[o];
    int seg = o >> 9, oo = o & 511, h = oo>>6, dd = oo&63;
    #pragma unroll
    for (int r=0;r<4;++r){
      int n = n0 + lg*4 + r;
      unsigned short val = f2bf(acc[s][r] + bias);
      if (seg==0)      Qh[(((size_t)(b*8+h))*2048+n)*64 + dd] = val;
      else if (seg==1) Kh[(((size_t)(b*8+h))*2048+n)*64 + dd] = val;
      else             Vt[(((size_t)(b*8+h))*64+dd)*2048 + n] = val;
    }
  }
}

// ---------------- K4: flash attention + rel-pos bias ----------------
// grid 512 = bh(16) x qtile(32); block 4 waves; wave: 16 q rows, JB=64
__global__ __launch_bounds__(256) void k_attn(const unsigned short* __restrict__ Qh,
                                              const unsigned short* __restrict__ Kh,
                                              const unsigned short* __restrict__ Vt,
                                              const float* __restrict__ rel,
                                              unsigned short* __restrict__ AO){
  int qt = blockIdx.x & 31, bh = blockIdx.x >> 5;
  int tid = threadIdx.x, wid = tid>>6, l = tid&63, lr = l&15, lg = l>>4;
  __shared__ float lut[512];
  __shared__ unsigned short pbuf[4][1024];   // per-wave 16x64 bf16, XOR-swizzled
  for (int s2 = tid; s2 < 500; s2 += 256){
    int bkt = (s2>=16)+(s2>=64)+(s2>=144)+(s2>=256)+(s2>=400);
    lut[s2] = rel[bkt];
  }
  __syncthreads();
  int q0 = qt*64 + wid*16;
  const unsigned short* Qb = Qh + (size_t)bh*2048*64;
  const unsigned short* Kb = Kh + (size_t)bh*2048*64;
  const unsigned short* Vb = Vt + (size_t)bh*64*2048;
  bfv8 qf0 = *(const bfv8*)(Qb + (size_t)(q0+lr)*64 + lg*8);
  bfv8 qf1 = *(const bfv8*)(Qb + (size_t)(q0+lr)*64 + 32 + lg*8);
  int di[4], hi4[4], wi4[4];
  #pragma unroll
  for (int r=0;r<4;++r){ int q = q0 + lg*4 + r; di[r]=q>>8; hi4[r]=(q>>4)&15; wi4[r]=q&15; }
  f4v oacc[4];
  #pragma unroll
  for (int i2=0;i2<4;++i2) oacc[i2] = (f4v){0.f,0.f,0.f,0.f};
  float m[4]    = {-1e30f,-1e30f,-1e30f,-1e30f};
  float lsum[4] = {0.f,0.f,0.f,0.f};
  unsigned short* pw = pbuf[wid];
  for (int jb=0; jb<2048; jb+=64){
    f4v sacc[4];
    #pragma unroll
    for (int t=0;t<4;++t) sacc[t] = (f4v){0.f,0.f,0.f,0.f};
    #pragma unroll
    for (int t=0;t<4;++t){
      bfv8 kf0 = *(const bfv8*)(Kb + (size_t)(jb + t*16 + lr)*64 + lg*8);
      bfv8 kf1 = *(const bfv8*)(Kb + (size_t)(jb + t*16 + lr)*64 + 32 + lg*8);
      sacc[t] = mfma16(qf0, kf0, sacc[t]);
      sacc[t] = mfma16(qf1, kf1, sacc[t]);
    }
    float pvv[4][4];
    #pragma unroll
    for (int t=0;t<4;++t){
      int j = jb + t*16 + lr;
      int dj=j>>8, hj=(j>>4)&15, wj=j&15;
      #pragma unroll
      for (int r=0;r<4;++r){
        int sd=di[r]-dj, sh=hi4[r]-hj, sw=wi4[r]-wj;
        int ssq = sd*sd+sh*sh+sw*sw;
        pvv[t][r] = sacc[t][r]*0.125f + lut[ssq];
      }
    }
    float alpha[4];
    #pragma unroll
    for (int r=0;r<4;++r){
      float v = fmaxf(fmaxf(pvv[0][r],pvv[1][r]),fmaxf(pvv[2][r],pvv[3][r]));
      v = fmaxf(v, __shfl_xor(v,1));
      v = fmaxf(v, __shfl_xor(v,2));
      v = fmaxf(v, __shfl_xor(v,4));
      v = fmaxf(v, __shfl_xor(v,8));
      float mn = fmaxf(m[r], v);
      alpha[r] = __expf(m[r]-mn);
      m[r] = mn;
      lsum[r] *= alpha[r];
    }
    float psum[4] = {0.f,0.f,0.f,0.f};
    #pragma unroll
    for (int t=0;t<4;++t){
      #pragma unroll
      for (int r=0;r<4;++r){
        float p = __expf(pvv[t][r]-m[r]);
        pvv[t][r] = p;
        psum[r] += p;
      }
    }
    #pragma unroll
    for (int r=0;r<4;++r){
      float v = psum[r];
      v += __shfl_xor(v,1); v += __shfl_xor(v,2);
      v += __shfl_xor(v,4); v += __shfl_xor(v,8);
      lsum[r] += v;
      #pragma unroll
      for (int d2=0;d2<4;++d2) oacc[d2][r] *= alpha[r];
    }
    // P -> per-wave LDS (XOR swizzle: byte ^= (row&7)<<4), no barrier (wave-private)
    #pragma unroll
    for (int t=0;t<4;++t){
      #pragma unroll
      for (int r=0;r<4;++r){
        int row = lg*4+r;
        int colb = (t*16+lr)*2;
        *(unsigned short*)((char*)pw + row*128 + (colb ^ ((row&7)<<4))) = f2bf(pvv[t][r]);
      }
    }
    #pragma unroll
    for (int kt=0;kt<2;++kt){
      int colb = kt*64 + lg*16;
      bfv8 pf = *(const bfv8*)((char*)pw + lr*128 + (colb ^ ((lr&7)<<4)));
      #pragma unroll
      for (int d2=0;d2<4;++d2){
        bfv8 vf = *(const bfv8*)(Vb + (size_t)(d2*16+lr)*2048 + jb + kt*32 + lg*8);
        oacc[d2] = mfma16(pf, vf, oacc[d2]);
      }
    }
  }
  int b = bh>>3, h = bh&7;
  #pragma unroll
  for (int r=0;r<4;++r){
    int n = q0 + lg*4 + r;
    float inv = 1.f/lsum[r];
    #pragma unroll
    for (int d2=0;d2<4;++d2){
      int d = d2*16+lr;
      AO[((size_t)(b*2048)+n)*512 + h*64 + d] = f2bf(oacc[d2][r]*inv);
    }
  }
}

// ---------------- K5: proj GEMM + bias + residual ----------------
// grid 512 = b(2) x otile(8) x ntile(32); wave: 16 o-rows x 64 n-cols (coalesced fp32 stores)
__global__ __launch_bounds__(256) void k_proj(const unsigned short* __restrict__ AO,
                                              const unsigned short* __restrict__ wb,
                                              const float* __restrict__ pb,
                                              const float* __restrict__ x,
                                              float* __restrict__ out){
  int nt = blockIdx.x & 31, ot = (blockIdx.x>>5)&7, b = blockIdx.x>>8;
  int tid = threadIdx.x, wid = tid>>6, l = tid&63, lr = l&15, lg = l>>4;
  int o0 = ot*64 + wid*16, n0 = nt*64;
  f4v acc[4];
  #pragma unroll
  for (int t=0;t<4;++t) acc[t] = (f4v){0.f,0.f,0.f,0.f};
  const unsigned short* arow = wb + (size_t)(o0+lr)*512 + lg*8;
  const unsigned short* brow = AO + ((size_t)(b*2048)+n0+lr)*512 + lg*8;
  for (int k=0;k<512;k+=32){
    bfv8 a = *(const bfv8*)(arow + k);
    #pragma unroll
    for (int t=0;t<4;++t){
      bfv8 bb = *(const bfv8*)(brow + t*8192 + k);
      acc[t] = mfma16(a, bb, acc[t]);
    }
  }
  #pragma unroll
  for (int r=0;r<4;++r){
    int o = o0 + lg*4 + r;
    float bias = pb[o];
    #pragma unroll
    for (int t=0;t<4;++t){
      int n = n0 + t*16 + lr;
      size_t idx = ((size_t)(b*512)+o)*2048 + n;
      out[idx] = acc[t][r] + bias + x[idx];
    }
  }
}

extern "C" void kernel_launch(void* const* d_in, const int* in_sizes, int n_in,
                              void* d_out, int out_size, void* d_ws, size_t ws_size,
                              hipStream_t stream){
  const float* x     = (const float*)d_in[0];
  const float* gnw   = (const float*)d_in[1];
  const float* gnb   = (const float*)d_in[2];
  const float* qkvw  = (const float*)d_in[3];
  const float* qkvb  = (const float*)d_in[4];
  const float* projw = (const float*)d_in[5];
  const float* projb = (const float*)d_in[6];
  const float* rel   = (const float*)d_in[7];
  float* out = (float*)d_out;
  char* ws = (char*)d_ws;
  // workspace layout (bytes), all 16B-aligned; total ~23.1 MB
  float2* part           = (float2*)ws;                       // 2 KB
  unsigned short* qkvwb  = (unsigned short*)(ws + 4096);      // 1536x512 bf16
  unsigned short* projwb = (unsigned short*)(ws + 1576960);   // 512x512 bf16
  unsigned short* hT     = (unsigned short*)(ws + 2101248);   // [2][2048][512]
  unsigned short* Qh     = (unsigned short*)(ws + 6295552);   // [2][8][2048][64]
  unsigned short* Kh     = (unsigned short*)(ws + 10489856);  // [2][8][2048][64]
  unsigned short* Vt     = (unsigned short*)(ws + 14684160);  // [2][8][64][2048]
  unsigned short* AO     = (unsigned short*)(ws + 18878464);  // [2][2048][512]

  hipLaunchKernelGGL(k_cvt,    dim3(768), dim3(256), 0, stream, qkvw, qkvwb);
  hipLaunchKernelGGL(k_cvt,    dim3(256), dim3(256), 0, stream, projw, projwb);
  hipLaunchKernelGGL(k_gnstat, dim3(256), dim3(256), 0, stream, x, part);
  hipLaunchKernelGGL(k_gnnorm, dim3(512), dim3(256), 0, stream, x, part, gnw, gnb, hT);
  hipLaunchKernelGGL(k_qkv,    dim3(768), dim3(256), 0, stream, hT, qkvwb, qkvb, Qh, Kh, Vt);
  hipLaunchKernelGGL(k_attn,   dim3(512), dim3(256), 0, stream, Qh, Kh, Vt, rel, AO);
  hipLaunchKernelGGL(k_proj,   dim3(512), dim3(256), 0, stream, AO, projwb, projb, x, out);
}

// Round 2
// 206.760 us; speedup vs baseline: 1.0293x; 1.0293x over previous
//
#include <hip/hip_runtime.h>

typedef __attribute__((ext_vector_type(8))) __bf16 bfv8;
typedef __attribute__((ext_vector_type(4))) float f4v;
typedef __attribute__((ext_vector_type(4))) unsigned short us4v;
typedef __attribute__((ext_vector_type(8))) unsigned short us8v;

static __device__ __forceinline__ unsigned short f2bf(float f){
  union { float f; unsigned u; } v; v.f = f;
  unsigned r = v.u + 0x7fffu + ((v.u >> 16) & 1u);
  return (unsigned short)(r >> 16);
}

static __device__ __forceinline__ unsigned cvtpk(float a, float b){
  unsigned r;
  asm("v_cvt_pk_bf16_f32 %0, %1, %2" : "=v"(r) : "v"(a), "v"(b));
  return r;
}

static __device__ __forceinline__ f4v mfma16(bfv8 a, bfv8 b, f4v c){
  return __builtin_amdgcn_mfma_f32_16x16x32_bf16(a, b, c, 0, 0, 0);
}

// ---------------- K0: fp32 -> bf16 convert (weights) ----------------
__global__ __launch_bounds__(256) void k_cvt(const float* __restrict__ src,
                                             unsigned short* __restrict__ dst){
  int i = blockIdx.x * 256 + threadIdx.x;
  float4 v = ((const float4*)src)[i];
  us4v o; o[0]=f2bf(v.x); o[1]=f2bf(v.y); o[2]=f2bf(v.z); o[3]=f2bf(v.w);
  *(us4v*)(dst + (size_t)i*4) = o;
}

// ---------------- K1: GroupNorm partial stats ----------------
__global__ __launch_bounds__(256) void k_gnstat(const float* __restrict__ x,
                                                float2* __restrict__ part){
  int bg = blockIdx.x >> 4, ch = blockIdx.x & 15;
  const float4* base = (const float4*)(x + (size_t)bg*131072 + (size_t)ch*8192);
  float s=0.f, ss=0.f;
  #pragma unroll
  for (int it=0; it<8; ++it){
    float4 v = base[threadIdx.x + it*256];
    s  += v.x+v.y+v.z+v.w;
    ss += v.x*v.x+v.y*v.y+v.z*v.z+v.w*v.w;
  }
  #pragma unroll
  for (int off=1; off<64; off<<=1){ s += __shfl_xor(s,off); ss += __shfl_xor(ss,off); }
  __shared__ float red[8];
  int wid = threadIdx.x >> 6, l = threadIdx.x & 63;
  if (l==0){ red[wid]=s; red[wid+4]=ss; }
  __syncthreads();
  if (threadIdx.x==0)
    part[blockIdx.x] = make_float2(red[0]+red[1]+red[2]+red[3],
                                   red[4]+red[5]+red[6]+red[7]);
}

// ---------------- K2: GroupNorm finalize + transpose to hT[b][n][c] bf16 ----------------
__global__ __launch_bounds__(256) void k_gnnorm(const float* __restrict__ x,
                                                const float2* __restrict__ part,
                                                const float* __restrict__ gnw,
                                                const float* __restrict__ gnb,
                                                unsigned short* __restrict__ hT){
  int nt = blockIdx.x & 31, ct = (blockIdx.x>>5)&7, b = blockIdx.x>>8;
  __shared__ float2 sms;
  __shared__ unsigned short tile[64][68];
  int tid = threadIdx.x;
  if (tid == 0){
    int bg = b*8 + ct;
    float s=0.f, ss=0.f;
    for (int i=0;i<16;++i){ float2 p = part[bg*16+i]; s+=p.x; ss+=p.y; }
    float mean = s * (1.f/131072.f);
    float var  = ss * (1.f/131072.f) - mean*mean;
    sms = make_float2(mean, rsqrtf(var + 1e-5f));
  }
  __syncthreads();
  float mean = sms.x, rstd = sms.y;
  int c0 = ct*64, n0 = nt*64;
  #pragma unroll
  for (int pass=0; pass<4; ++pass){
    int i = (tid>>4) + pass*16;
    int fc = tid & 15;
    int c = c0 + i;
    float w  = gnw[c]*rstd;
    float bb = gnb[c] - mean*w;
    float4 v = *(const float4*)(x + ((size_t)(b*512+c))*2048 + n0 + fc*4);
    tile[i][fc*4+0] = f2bf(v.x*w+bb);
    tile[i][fc*4+1] = f2bf(v.y*w+bb);
    tile[i][fc*4+2] = f2bf(v.z*w+bb);
    tile[i][fc*4+3] = f2bf(v.w*w+bb);
  }
  __syncthreads();
  #pragma unroll
  for (int pass=0; pass<2; ++pass){
    int r  = (tid>>3) + pass*32;
    int c8 = tid & 7;
    us8v o;
    #pragma unroll
    for (int u=0;u<8;++u) o[u] = tile[c8*8+u][r];
    *(us8v*)(hT + ((size_t)(b*2048 + n0 + r))*512 + c0 + c8*8) = o;
  }
}

// ---------------- K3: qkv GEMM ----------------
__global__ __launch_bounds__(256) void k_qkv(const unsigned short* __restrict__ hT,
                                             const unsigned short* __restrict__ wb,
                                             const float* __restrict__ qb,
                                             unsigned short* __restrict__ Qh,
                                             unsigned short* __restrict__ Kh,
                                             unsigned short* __restrict__ Vt){
  int bid = blockIdx.x;
  int ot = bid % 12; int t2 = bid / 12; int nt = t2 & 31; int b = t2 >> 5;
  int tid = threadIdx.x, wid = tid>>6, l = tid&63, lr = l&15, lg = l>>4;
  int n0 = nt*64 + wid*16, o0 = ot*128;
  f4v acc[8];
  #pragma unroll
  for (int s=0;s<8;++s) acc[s] = (f4v){0.f,0.f,0.f,0.f};
  const unsigned short* arow = hT + ((size_t)(b*2048 + n0 + lr))*512 + lg*8;
  const unsigned short* brow = wb + (size_t)(o0 + lr)*512 + lg*8;
  for (int k=0;k<512;k+=32){
    bfv8 a = *(const bfv8*)(arow + k);
    #pragma unroll
    for (int s=0;s<8;++s){
      bfv8 bb = *(const bfv8*)(brow + s*8192 + k);
      acc[s] = mfma16(a, bb, acc[s]);
    }
  }
  #pragma unroll
  for (int s=0;s<8;++s){
    int o = o0 + s*16 + lr;
    float bias = qb[o];
    int seg = o >> 9, oo = o & 511, h = oo>>6, dd = oo&63;
    #pragma unroll
    for (int r=0;r<4;++r){
      int n = n0 + lg*4 + r;
      unsigned short val = f2bf(acc[s][r] + bias);
      if (seg==0)      Qh[(((size_t)(b*8+h))*2048+n)*64 + dd] = val;
      else if (seg==1) Kh[(((size_t)(b*8+h))*2048+n)*64 + dd] = val;
      else             Vt[(((size_t)(b*8+h))*64+dd)*2048 + n] = val;
    }
  }
}

// ---------------- K4: flash attention v2 ----------------
// swapped QK^T (S^T), static max, deferred row-sum, 32-entry conflict-free LUT,
// packed P relayout, XCD-chunked block remap (2 heads per XCD).
__global__ __launch_bounds__(256) void k_attn(const unsigned short* __restrict__ Qh,
                                              const unsigned short* __restrict__ Kh,
                                              const unsigned short* __restrict__ Vt,
                                              const float* __restrict__ rel,
                                              unsigned short* __restrict__ AO){
  int did = blockIdx.x;
  int bh = (did & 7)*2 + ((did >> 8) & 1);   // 64 consecutive-XCD blocks share 2 heads
  int qt = (did >> 3) & 31;
  int tid = threadIdx.x, wid = tid>>6, l = tid&63, lr = l&15, lg = l>>4;
  __shared__ float slut[32];
  __shared__ unsigned short pbuf[4][1024];
  if (tid < 32){
    int bkt = (tid>=1)+(tid>=4)+(tid>=9)+(tid>=16)+(tid>=25);
    slut[tid] = rel[bkt];
  }
  __syncthreads();
  int q0 = qt*64 + wid*16;
  int dq = q0 >> 8, hq = (q0 >> 4) & 15;     // wave-uniform (q0 is 16-aligned)
  int swsq[4];
  #pragma unroll
  for (int r=0;r<4;++r){ int sw = lr - (lg*4+r); swsq[r] = sw*sw; }
  const unsigned short* Qb = Qh + (size_t)bh*131072;
  const unsigned short* Kb = Kh + (size_t)bh*131072;
  const unsigned short* Vb = Vt + (size_t)bh*131072;
  bfv8 qf0 = *(const bfv8*)(Qb + (size_t)(q0+lr)*64 + lg*8);
  bfv8 qf1 = *(const bfv8*)(Qb + (size_t)(q0+lr)*64 + 32 + lg*8);
  f4v oacc[4];
  #pragma unroll
  for (int i2=0;i2<4;++i2) oacc[i2] = (f4v){0.f,0.f,0.f,0.f};
  float lsumL = 0.f;
  char* pw = (char*)pbuf[wid];
  int swz = (lr&7)<<4;
  for (int it=0; it<32; ++it){
    int jb = it*64;
    f4v sacc[4];
    #pragma unroll
    for (int t=0;t<4;++t) sacc[t] = (f4v){0.f,0.f,0.f,0.f};
    #pragma unroll
    for (int t=0;t<4;++t){
      const unsigned short* kr = Kb + (size_t)(jb + t*16 + lr)*64 + lg*8;
      sacc[t] = mfma16(*(const bfv8*)kr, qf0, sacc[t]);        // S^T: A=K rows, B=Q rows
      sacc[t] = mfma16(*(const bfv8*)(kr+32), qf1, sacc[t]);
    }
    int sdh[4];
    {
      int dj = it>>2; int sd = dq-dj; int sds = sd*sd;
      int hj0 = (it&3)*4;
      #pragma unroll
      for (int t=0;t<4;++t){ int sh = hq - (hj0+t); sdh[t] = sds + sh*sh; }
    }
    float p[4][4];
    #pragma unroll
    for (int t=0;t<4;++t){
      #pragma unroll
      for (int r=0;r<4;++r){
        float bias = slut[(sdh[t]+swsq[r])>>4];
        float e = __expf(fmaf(sacc[t][r], 0.125f, bias));
        p[t][r] = e;
        lsumL += e;
      }
    }
    #pragma unroll
    for (int t=0;t<4;++t){
      uint2 w;
      w.x = cvtpk(p[t][0], p[t][1]);
      w.y = cvtpk(p[t][2], p[t][3]);
      *(uint2*)(pw + lr*128 + ((32*t + 8*lg) ^ swz)) = w;
    }
    #pragma unroll
    for (int kt=0;kt<2;++kt){
      bfv8 pf = *(const bfv8*)(pw + lr*128 + ((64*kt + 16*lg) ^ swz));
      #pragma unroll
      for (int d2=0;d2<4;++d2){
        bfv8 vf = *(const bfv8*)(Vb + (size_t)(d2*16+lr)*2048 + jb + kt*32 + lg*8);
        oacc[d2] = mfma16(pf, vf, oacc[d2]);
      }
    }
  }
  lsumL += __shfl_xor(lsumL, 16);
  lsumL += __shfl_xor(lsumL, 32);
  int b = bh>>3, h = bh&7;
  #pragma unroll
  for (int r=0;r<4;++r){
    float inv = 1.f / __shfl(lsumL, lg*4+r);
    int n = q0 + lg*4 + r;
    #pragma unroll
    for (int d2=0;d2<4;++d2){
      int d = d2*16+lr;
      AO[((size_t)(b*2048)+n)*512 + h*64 + d] = f2bf(oacc[d2][r]*inv);
    }
  }
}

// ---------------- K5: proj GEMM + bias + residual ----------------
__global__ __launch_bounds__(256) void k_proj(const unsigned short* __restrict__ AO,
                                              const unsigned short* __restrict__ wb,
                                              const float* __restrict__ pb,
                                              const float* __restrict__ x,
                                              float* __restrict__ out){
  int nt = blockIdx.x & 31, ot = (blockIdx.x>>5)&7, b = blockIdx.x>>8;
  int tid = threadIdx.x, wid = tid>>6, l = tid&63, lr = l&15, lg = l>>4;
  int o0 = ot*64 + wid*16, n0 = nt*64;
  f4v acc[4];
  #pragma unroll
  for (int t=0;t<4;++t) acc[t] = (f4v){0.f,0.f,0.f,0.f};
  const unsigned short* arow = wb + (size_t)(o0+lr)*512 + lg*8;
  const unsigned short* brow = AO + ((size_t)(b*2048)+n0+lr)*512 + lg*8;
  for (int k=0;k<512;k+=32){
    bfv8 a = *(const bfv8*)(arow + k);
    #pragma unroll
    for (int t=0;t<4;++t){
      bfv8 bb = *(const bfv8*)(brow + t*8192 + k);
      acc[t] = mfma16(a, bb, acc[t]);
    }
  }
  #pragma unroll
  for (int r=0;r<4;++r){
    int o = o0 + lg*4 + r;
    float bias = pb[o];
    #pragma unroll
    for (int t=0;t<4;++t){
      int n = n0 + t*16 + lr;
      size_t idx = ((size_t)(b*512)+o)*2048 + n;
      out[idx] = acc[t][r] + bias + x[idx];
    }
  }
}

extern "C" void kernel_launch(void* const* d_in, const int* in_sizes, int n_in,
                              void* d_out, int out_size, void* d_ws, size_t ws_size,
                              hipStream_t stream){
  const float* x     = (const float*)d_in[0];
  const float* gnw   = (const float*)d_in[1];
  const float* gnb   = (const float*)d_in[2];
  const float* qkvw  = (const float*)d_in[3];
  const float* qkvb  = (const float*)d_in[4];
  const float* projw = (const float*)d_in[5];
  const float* projb = (const float*)d_in[6];
  const float* rel   = (const float*)d_in[7];
  float* out = (float*)d_out;
  char* ws = (char*)d_ws;
  float2* part           = (float2*)ws;                       // 2 KB
  unsigned short* qkvwb  = (unsigned short*)(ws + 4096);      // 1536x512 bf16
  unsigned short* projwb = (unsigned short*)(ws + 1576960);   // 512x512 bf16
  unsigned short* hT     = (unsigned short*)(ws + 2101248);   // [2][2048][512]
  unsigned short* Qh     = (unsigned short*)(ws + 6295552);   // [2][8][2048][64]
  unsigned short* Kh     = (unsigned short*)(ws + 10489856);  // [2][8][2048][64]
  unsigned short* Vt     = (unsigned short*)(ws + 14684160);  // [2][8][64][2048]
  unsigned short* AO     = (unsigned short*)(ws + 18878464);  // [2][2048][512]

  hipLaunchKernelGGL(k_cvt,    dim3(768), dim3(256), 0, stream, qkvw, qkvwb);
  hipLaunchKernelGGL(k_cvt,    dim3(256), dim3(256), 0, stream, projw, projwb);
  hipLaunchKernelGGL(k_gnstat, dim3(256), dim3(256), 0, stream, x, part);
  hipLaunchKernelGGL(k_gnnorm, dim3(512), dim3(256), 0, stream, x, part, gnw, gnb, hT);
  hipLaunchKernelGGL(k_qkv,    dim3(768), dim3(256), 0, stream, hT, qkvwb, qkvb, Qh, Kh, Vt);
  hipLaunchKernelGGL(k_attn,   dim3(512), dim3(256), 0, stream, Qh, Kh, Vt, rel, AO);
  hipLaunchKernelGGL(k_proj,   dim3(512), dim3(256), 0, stream, AO, projwb, projb, x, out);
}